// Round 5
// baseline (95.537 us; speedup 1.0000x reference)
//
#include <hip/hip_runtime.h>
#include <hip/hip_bf16.h>

#define N 16384
#define D 128
#define NTI 128              // 128x128 tiles per dim
#define GBLK 2112            // sum_{u<32} 4*(32-u) chunk blocks (chunks of 4 tiles)
#define B_HALF 8192          // positive-pair offset

typedef __attribute__((ext_vector_type(8))) short short8;
typedef __attribute__((ext_vector_type(4))) float f32x4;

__device__ inline unsigned short f2bf(float x) {
    union { float f; unsigned u; } c; c.f = x;
    unsigned r = c.u + 0x7fffu + ((c.u >> 16) & 1u);   // RNE
    return (unsigned short)(r >> 16);
}

// ---------------------------------------------------------------- prep ----
// 8 threads per row-pair (i, i+8192). Slab layout [panel][ks][row][8 elems].
__global__ __launch_bounds__(256)
void prep_kernel(const float* __restrict__ feats, unsigned short* __restrict__ fbP,
                 float* __restrict__ sq, float* __restrict__ rsum,
                 float* __restrict__ qii) {
    const int g  = blockIdx.x * 256 + threadIdx.x;   // 0..65535
    const int p  = g >> 3;                           // pair 0..8191
    const int t8 = g & 7;                            // 16-col segment
    const int i0 = p, i1 = p + B_HALF;
    const float4* ra = reinterpret_cast<const float4*>(feats + (size_t)i0 * D + t8 * 16);
    const float4* rb = reinterpret_cast<const float4*>(feats + (size_t)i1 * D + t8 * 16);
    char* da = (char*)fbP + (size_t)(i0 >> 7) * 32768 + (size_t)(i0 & 127) * 16;
    char* db = (char*)fbP + (size_t)(i1 >> 7) * 32768 + (size_t)(i1 & 127) * 16;
    float sa = 0.f, sb = 0.f, dot = 0.f;
#pragma unroll
    for (int c = 0; c < 2; ++c) {                    // two 8-col (ks) chunks
        float4 x0 = ra[2 * c], x1 = ra[2 * c + 1];
        float4 y0 = rb[2 * c], y1 = rb[2 * c + 1];
        sa  += x0.x * x0.x + x0.y * x0.y + x0.z * x0.z + x0.w * x0.w
             + x1.x * x1.x + x1.y * x1.y + x1.z * x1.z + x1.w * x1.w;
        sb  += y0.x * y0.x + y0.y * y0.y + y0.z * y0.z + y0.w * y0.w
             + y1.x * y1.x + y1.y * y1.y + y1.z * y1.z + y1.w * y1.w;
        dot += x0.x * y0.x + x0.y * y0.y + x0.z * y0.z + x0.w * y0.w
             + x1.x * y1.x + x1.y * y1.y + x1.z * y1.z + x1.w * y1.w;
        short8 ca, cb;
        ca[0] = f2bf(x0.x); ca[1] = f2bf(x0.y); ca[2] = f2bf(x0.z); ca[3] = f2bf(x0.w);
        ca[4] = f2bf(x1.x); ca[5] = f2bf(x1.y); ca[6] = f2bf(x1.z); ca[7] = f2bf(x1.w);
        cb[0] = f2bf(y0.x); cb[1] = f2bf(y0.y); cb[2] = f2bf(y0.z); cb[3] = f2bf(y0.w);
        cb[4] = f2bf(y1.x); cb[5] = f2bf(y1.y); cb[6] = f2bf(y1.z); cb[7] = f2bf(y1.w);
        *reinterpret_cast<short8*>(da + (2 * t8 + c) * 2048) = ca;
        *reinterpret_cast<short8*>(db + (2 * t8 + c) * 2048) = cb;
    }
    sa  += __shfl_xor(sa, 1);  sa  += __shfl_xor(sa, 2);  sa  += __shfl_xor(sa, 4);
    sb  += __shfl_xor(sb, 1);  sb  += __shfl_xor(sb, 2);  sb  += __shfl_xor(sb, 4);
    dot += __shfl_xor(dot, 1); dot += __shfl_xor(dot, 2); dot += __shfl_xor(dot, 4);
    if (t8 == 0) {
        sq[i0] = sa; sq[i1] = sb;
        rsum[i0] = 0.f; rsum[i1] = 0.f;
        float d2 = fmaxf(sa + sb - 2.f * dot, 0.f);
        float q = 1.f / (d2 + 1.f);
        qii[i0] = q; qii[i1] = q;
    }
}

// ---------------------------------------------------------------- gram ----
// 512 threads = 8 waves in a 4x2 grid; per-wave output 32x64. A-panel in
// VGPRs (32 regs); B double-buffered in two 16 KiB half-K LDS buffers.
// 8 half-K phases per 4-tile chunk; stage(p+1) issued right after the
// phase-p barrier; NO vmem in the loop body (col-sums via ds_add, sq from
// LDS) so vmcnt(0) at each phase top waits ONLY on that phase's 2 loads.
__global__ __launch_bounds__(512, 4)
void gram_kernel(const unsigned short* __restrict__ fbP, const float* __restrict__ sq,
                 float* __restrict__ rsum) {
    __shared__ __align__(16) unsigned short lB[2][8 * 128 * 8];   // 2 x 16 KiB
    __shared__ float cs[512];     // per-block col sums, 4 tiles x 128
    __shared__ float sqL[512];    // sq slice for the 4 B-panels

    // XCD-chunked swizzle (2112 = 8 * 264, bijective)
    const int bid = (blockIdx.x & 7) * (GBLK / 8) + (blockIdx.x >> 3);

    // rows grouped by 4 (u = ti>>2): row group u has cnt = 32-u chunks/row.
    int u = (int)((130.0f - sqrtf(16900.0f - 8.0f * (float)bid)) * 0.25f);
    if (u < 0) u = 0; if (u > 31) u = 31;
    while (u > 0 && 2 * u * (65 - u) > bid) --u;
    while (2 * (u + 1) * (64 - u) <= bid) ++u;
    int rem = bid - 2 * u * (65 - u);
    const int cnt = 32 - u;
    int sub = 0;
    while (rem >= cnt) { rem -= cnt; ++sub; }
    const int ti  = 4 * u + sub;
    const int tj0 = ti + 4 * rem;
    const int nt  = (NTI - tj0 < 4) ? (NTI - tj0) : 4;

    const int tid  = threadIdx.x;
    const int lane = tid & 63;
    const int wid  = tid >> 6;         // 0..7
    const int wr   = wid >> 1;         // 0..3  (row wave)
    const int wc   = wid & 1;          // 0..1  (col wave)
    const int lrow = lane & 15;
    const int lk   = lane >> 4;

    // ---- prologue ----
    const char* pa = (const char*)fbP + (size_t)ti * 32768;
    short8 a[4][2];                    // [kk][m] : 32 VGPRs
#pragma unroll
    for (int kk = 0; kk < 4; ++kk)
#pragma unroll
        for (int m = 0; m < 2; ++m)
            a[kk][m] = *reinterpret_cast<const short8*>(
                pa + (kk * 4 + lk) * 2048 + (wr * 32 + m * 16 + lrow) * 16);

    float sqa[2][4];
#pragma unroll
    for (int m = 0; m < 2; ++m) {
        const float4 v = *reinterpret_cast<const float4*>(
            sq + ti * 128 + wr * 32 + m * 16 + lk * 4);
        sqa[m][0] = v.x; sqa[m][1] = v.y; sqa[m][2] = v.z; sqa[m][3] = v.w;
    }

    cs[tid] = 0.f;
    // stage sq slice for the 4 B panels (2 KiB; waves 0,1)
    if (wid < 2) {
        const char* ssrc = (const char*)(sq + tj0 * 128) + wid * 1024 + lane * 16;
        __builtin_amdgcn_global_load_lds(
            (const __attribute__((address_space(1))) void*)ssrc,
            (__attribute__((address_space(3))) void*)((char*)sqL + wid * 1024 + lane * 16),
            16, 0, 0);
    }
    // stage B phase 0 (tile tj0, half 0)
    {
        const char* src = (const char*)fbP + (size_t)tj0 * 32768;
#pragma unroll
        for (int it = 0; it < 2; ++it) {
            const int lbase = it * 8192 + wid * 1024;
            __builtin_amdgcn_global_load_lds(
                (const __attribute__((address_space(1))) void*)(src + lbase + lane * 16),
                (__attribute__((address_space(3))) void*)((char*)lB[0] + lbase), 16, 0, 0);
        }
    }

    float racc[2][4];
#pragma unroll
    for (int m = 0; m < 2; ++m)
#pragma unroll
        for (int r = 0; r < 4; ++r) racc[m][r] = 0.f;

    __syncthreads();   // drains vm (A, sq, stage0) + lgkm (cs zero) + barrier

    f32x4 acc[2][4];

    // ---- 8 half-K phases, depth-1 prefetch, counted-exact vmcnt ----
#pragma unroll
    for (int p = 0; p < 8; ++p) {
        if (p < 2 * nt) {              // block-uniform
            if (p > 0) {
                asm volatile("s_waitcnt vmcnt(0)" ::: "memory");  // phase-p stage done
                __builtin_amdgcn_sched_barrier(0);
                __builtin_amdgcn_s_barrier();
                __builtin_amdgcn_sched_barrier(0);
            }
            const int t = p >> 1, h = p & 1;

            if (p + 1 < 2 * nt) {      // prefetch next half-panel
                const int t2 = (p + 1) >> 1, h2 = (p + 1) & 1;
                const char* src = (const char*)fbP + (size_t)(tj0 + t2) * 32768 + h2 * 16384;
                unsigned short* dst = lB[(p + 1) & 1];
#pragma unroll
                for (int it = 0; it < 2; ++it) {
                    const int lbase = it * 8192 + wid * 1024;
                    __builtin_amdgcn_global_load_lds(
                        (const __attribute__((address_space(1))) void*)(src + lbase + lane * 16),
                        (__attribute__((address_space(3))) void*)((char*)dst + lbase), 16, 0, 0);
                }
            }

            if (h == 0) {
#pragma unroll
                for (int m = 0; m < 2; ++m)
#pragma unroll
                    for (int n = 0; n < 4; ++n) acc[m][n] = (f32x4){0.f, 0.f, 0.f, 0.f};
            }

            const char* lbuf = (const char*)lB[p & 1];
            __builtin_amdgcn_s_setprio(1);
#pragma unroll
            for (int kh = 0; kh < 2; ++kh) {
                const int kk = 2 * h + kh;     // global k-slab group (A index)
                short8 b[4];
#pragma unroll
                for (int n = 0; n < 4; ++n)
                    b[n] = *reinterpret_cast<const short8*>(
                        lbuf + (kh * 4 + lk) * 2048 + (wc * 64 + n * 16 + lrow) * 16);
#pragma unroll
                for (int m = 0; m < 2; ++m)
#pragma unroll
                    for (int n = 0; n < 4; ++n)
                        acc[m][n] = __builtin_amdgcn_mfma_f32_16x16x32_bf16(
                            a[kk][m], b[n], acc[m][n], 0, 0, 0);
            }
            __builtin_amdgcn_s_setprio(0);

            if (h == 1) {              // tile t epilogue (acc complete)
                float sqb1[4];
#pragma unroll
                for (int n = 0; n < 4; ++n)
                    sqb1[n] = sqL[t * 128 + wc * 64 + n * 16 + lrow] + 1.0f;
                float cloc[4] = {0.f, 0.f, 0.f, 0.f};
#pragma unroll
                for (int m = 0; m < 2; ++m)
#pragma unroll
                    for (int n = 0; n < 4; ++n)
#pragma unroll
                        for (int r = 0; r < 4; ++r) {
                            float x = fmaf(-2.f, acc[m][n][r], sqa[m][r]);
                            float q = __builtin_amdgcn_rcpf(fmaxf(x + sqb1[n], 1.0f));
                            racc[m][r] += q;
                            cloc[n] += q;
                        }
                if (tj0 + t != ti) {   // diagonal tile: rows==cols, skip col side
#pragma unroll
                    for (int n = 0; n < 4; ++n) {
                        float v = cloc[n];
                        v += __shfl_xor(v, 16);
                        v += __shfl_xor(v, 32);
                        if (lane < 16)
                            atomicAdd(&cs[t * 128 + wc * 64 + n * 16 + lrow], v);
                    }
                }
            }
        }
    }

    __syncthreads();   // all ds_adds + last reads done

    // ---- flush: row sums (registers) + col sums (LDS) -> global ----
#pragma unroll
    for (int m = 0; m < 2; ++m)
#pragma unroll
        for (int r = 0; r < 4; ++r) {
            float v = racc[m][r];
            v += __shfl_xor(v, 1);
            v += __shfl_xor(v, 2);
            v += __shfl_xor(v, 4);
            v += __shfl_xor(v, 8);
            if (lrow == 0)
                atomicAdd(&rsum[ti * 128 + wr * 32 + m * 16 + lk * 4 + r], v);
        }
    {
        const int t = tid >> 7, row = tid & 127;
        if (t < nt && tj0 + t != ti)
            atomicAdd(&rsum[(tj0 + t) * 128 + row], cs[tid]);
    }
}

// -------------------------------------------------------------- finish ----
__global__ __launch_bounds__(256)
void finish1_kernel(const float* __restrict__ rsum, const float* __restrict__ qii,
                    float* __restrict__ partial) {
    __shared__ float red[4];
    const int i = blockIdx.x * 256 + threadIdx.x;
    float v = __logf(rsum[i]) - __logf(qii[i]);   // repulsive + attractive
#pragma unroll
    for (int m = 32; m >= 1; m >>= 1) v += __shfl_xor(v, m);
    if ((threadIdx.x & 63) == 0) red[threadIdx.x >> 6] = v;
    __syncthreads();
    if (threadIdx.x == 0) partial[blockIdx.x] = red[0] + red[1] + red[2] + red[3];
}

__global__ __launch_bounds__(64)
void finish2_kernel(const float* __restrict__ partial, unsigned* __restrict__ out) {
    float v = partial[threadIdx.x];
#pragma unroll
    for (int m = 32; m >= 1; m >>= 1) v += __shfl_xor(v, m);
    if (threadIdx.x == 0) {
        float val = v / (float)N;
        // dtype hedge: high 16 bits = f32 high half, low 16 bits = bf16(val).
        union { float f; unsigned u; } c; c.f = val;
        out[0] = (c.u & 0xFFFF0000u) | (unsigned)f2bf(val);
    }
}

// ---------------------------------------------------------------- host ----
extern "C" void kernel_launch(void* const* d_in, const int* in_sizes, int n_in,
                              void* d_out, int out_size, void* d_ws, size_t ws_size,
                              hipStream_t stream) {
    const float* feats = (const float*)d_in[0];   // idx (d_in[1]) unused by reference
    char* ws = (char*)d_ws;
    unsigned short* fbP = (unsigned short*)ws;                              // 4 MiB
    float* sq      = (float*)(ws + (size_t)N * D * 2);                      // 64 KiB
    float* rsum    = (float*)(ws + (size_t)N * D * 2 + (size_t)N * 4);      // 64 KiB
    float* qii     = (float*)(ws + (size_t)N * D * 2 + (size_t)N * 8);      // 64 KiB
    float* partial = (float*)(ws + (size_t)N * D * 2 + (size_t)N * 12);     // 256 B

    hipLaunchKernelGGL(prep_kernel, dim3(256), dim3(256), 0, stream,
                       feats, fbP, sq, rsum, qii);
    hipLaunchKernelGGL(gram_kernel, dim3(GBLK), dim3(512), 0, stream,
                       fbP, sq, rsum);
    hipLaunchKernelGGL(finish1_kernel, dim3(64), dim3(256), 0, stream,
                       rsum, qii, partial);
    hipLaunchKernelGGL(finish2_kernel, dim3(1), dim3(64), 0, stream,
                       partial, (unsigned*)d_out);
}